// Round 8
// baseline (1847.527 us; speedup 1.0000x reference)
//
#include <hip/hip_runtime.h>

#define D128 128
#define NT 101
#define TDEC 512
#define PSTR 112            // padded p row: 4 quarters of 28 floats (16B aligned)
#define VPITCH 17           // VH inner stride (odd -> 2-way bank aliasing, free)
#define VGPP (112*VPITCH)   // per-head VH pitch = 1904 floats

// ---- decode LDS layout (floats) ----
#define VH_OFF   0                       // [8][112][17] V slices (zero-padded rows)
#define P_OFF    (VH_OFF + 8*VGPP)       // 8 x PSTR
#define LGH_OFF  (P_OFF + 8*PSTR)        // 8 x 104 logit partials
#define O_OFFS   (LGH_OFF + 8*104)       // 128
#define QV_OFF   (O_OFFS + 128)          // 128  raw QA row of current selection
#define BC_OFF   (QV_OFF + 128)          // 4  broadcast {dyn, depotf, bix, -}
#define LDS_FLOATS (BC_OFF + 4)          // 17220 floats = 68,880 B -> 2 WG/CU

#define INV_D_CONST 0.08838834764831845f

__device__ __forceinline__ int read_scalar_int(const void* p){
    unsigned u = *(const unsigned*)p;
    if (u < 1000000u) return (int)u;
    return (int)__uint_as_float(u);
}
__device__ __forceinline__ float read_scalar_float(const void* p){
    unsigned u = *(const unsigned*)p;
    if (u < 1000000u) return (float)(int)u;
    return __uint_as_float(u);
}

// ---- DPP cross-lane helpers (VALU pipe, no DS) ----
template<int C> __device__ __forceinline__ float dppf(float x){
    return __int_as_float(__builtin_amdgcn_update_dpp(
        __float_as_int(x), __float_as_int(x), C, 0xF, 0xF, false));
}
template<int C> __device__ __forceinline__ int dppi(int x){
    return __builtin_amdgcn_update_dpp(x, x, C, 0xF, 0xF, false);
}
__device__ __forceinline__ float wave_sum64(float v){
    v += dppf<0xB1>(v); v += dppf<0x4E>(v); v += dppf<0x141>(v); v += dppf<0x140>(v);
    v += __shfl_xor(v, 16, 64); v += __shfl_xor(v, 32, 64); return v;
}
__device__ __forceinline__ float wave_max64(float v){
    v = fmaxf(v, dppf<0xB1>(v)); v = fmaxf(v, dppf<0x4E>(v));
    v = fmaxf(v, dppf<0x141>(v)); v = fmaxf(v, dppf<0x140>(v));
    v = fmaxf(v, __shfl_xor(v, 16, 64)); v = fmaxf(v, __shfl_xor(v, 32, 64)); return v;
}
__device__ __forceinline__ void wave_argmax64(float& v, int& i){
    { float ov = dppf<0xB1>(v);        int oi = dppi<0xB1>(i);        if (ov>v || (ov==v && oi<i)){v=ov;i=oi;} }
    { float ov = dppf<0x4E>(v);        int oi = dppi<0x4E>(i);        if (ov>v || (ov==v && oi<i)){v=ov;i=oi;} }
    { float ov = dppf<0x141>(v);       int oi = dppi<0x141>(i);       if (ov>v || (ov==v && oi<i)){v=ov;i=oi;} }
    { float ov = dppf<0x140>(v);       int oi = dppi<0x140>(i);       if (ov>v || (ov==v && oi<i)){v=ov;i=oi;} }
    { float ov = __shfl_xor(v,16,64);  int oi = __shfl_xor(i,16,64);  if (ov>v || (ov==v && oi<i)){v=ov;i=oi;} }
    { float ov = __shfl_xor(v,32,64);  int oi = __shfl_xor(i,32,64);  if (ov>v || (ov==v && oi<i)){v=ov;i=oi;} }
}

// ---------------- weight folding (unchanged) ----------------
__global__ __launch_bounds__(512) void prep_w2(
        const float* __restrict__ fc_w, const float* __restrict__ attn_w,
        const float* __restrict__ prob_k, const float* __restrict__ attn_fc,
        const float* __restrict__ attn_k, const float* __restrict__ attn_v,
        float* __restrict__ Wcat, float* __restrict__ wlast){
    int i = blockIdx.x, t = threadIdx.x;
    if (i < 128){
        if (t < 128){
            Wcat[i*512 + t] = attn_k[i*D128 + t];
        } else if (t < 256){
            int j = t - 128;
            Wcat[i*512 + 128 + j] = attn_v[i*D128 + j];
        } else if (t < 384){
            int j = t - 256; float acc = 0.f;
            for (int e = 0; e < D128; ++e) acc += prob_k[i*D128+e]*attn_fc[j*D128+e];
            Wcat[i*512 + 256 + j] = acc;
        } else {
            int j = t - 384; float acc = 0.f;
            for (int e = 0; e < D128; ++e) acc += fc_w[i*D128+e]*attn_w[e*D128+j];
            Wcat[i*512 + 384 + j] = acc;
        }
    } else if (t < 128){
        float acc = 0.f;
        for (int e = 0; e < D128; ++e) acc += fc_w[128*D128+e]*attn_w[e*D128+t];
        wlast[t] = acc;
    }
}

__global__ __launch_bounds__(128) void prep_pq(
        const float* __restrict__ pool, const float* __restrict__ fc1_w,
        const float* __restrict__ attn_w, float* __restrict__ pq){
    __shared__ float s1[128], s2[128];
    int b = blockIdx.x, t = threadIdx.x;
    s1[t] = pool[(size_t)b*D128 + t];
    __syncthreads();
    float a = 0.f;
    for (int i = 0; i < D128; ++i) a += s1[i]*fc1_w[i*D128 + t];
    s2[t] = a;
    __syncthreads();
    float a2 = 0.f;
    for (int i = 0; i < D128; ++i) a2 += s2[i]*attn_w[i*D128 + t];
    pq[(size_t)b*D128 + t] = a2;
}

__global__ __launch_bounds__(256) void gemm_prep(
        const float* __restrict__ enc, const float* __restrict__ Wcat,
        const float* __restrict__ pq, int M,
        float* __restrict__ KVP, float* __restrict__ QA){
    __shared__ float As[64*132];
    const int t = threadIdx.x;
    const int m0 = blockIdx.x * 64;
    const int cb0 = blockIdx.y * 64;
    for (int i = t; i < 64*32; i += 256){
        int row = i >> 5, c4 = (i & 31) << 2;
        float4 val = make_float4(0.f,0.f,0.f,0.f);
        if (m0 + row < M) val = *(const float4*)(enc + (size_t)(m0+row)*D128 + c4);
        *(float4*)&As[row*132 + c4] = val;
    }
    __syncthreads();
    const int tx = t & 15, ty = t >> 4;
    float acc[4][4];
    #pragma unroll
    for (int i = 0; i < 4; ++i)
        #pragma unroll
        for (int j = 0; j < 4; ++j) acc[i][j] = 0.f;
    const float* wp = Wcat + cb0 + tx*4;
    #pragma unroll 4
    for (int k = 0; k < 128; ++k){
        float4 bv = *(const float4*)(wp + (size_t)k*512);
        float a0 = As[(ty*4+0)*132 + k];
        float a1 = As[(ty*4+1)*132 + k];
        float a2 = As[(ty*4+2)*132 + k];
        float a3 = As[(ty*4+3)*132 + k];
        acc[0][0] += a0*bv.x; acc[0][1] += a0*bv.y; acc[0][2] += a0*bv.z; acc[0][3] += a0*bv.w;
        acc[1][0] += a1*bv.x; acc[1][1] += a1*bv.y; acc[1][2] += a1*bv.z; acc[1][3] += a1*bv.w;
        acc[2][0] += a2*bv.x; acc[2][1] += a2*bv.y; acc[2][2] += a2*bv.z; acc[2][3] += a2*bv.w;
        acc[3][0] += a3*bv.x; acc[3][1] += a3*bv.y; acc[3][2] += a3*bv.z; acc[3][3] += a3*bv.w;
    }
    #pragma unroll
    for (int rr = 0; rr < 4; ++rr){
        int m = m0 + ty*4 + rr;
        if (m >= M) continue;
        if (cb0 < 384){
            *(float4*)&KVP[(size_t)m*384 + cb0 + tx*4] =
                make_float4(acc[rr][0], acc[rr][1], acc[rr][2], acc[rr][3]);
        } else {
            int bb = m / NT;
            int c = cb0 - 384 + tx*4;
            float4 pv = *(const float4*)(pq + (size_t)bb*D128 + c);
            *(float4*)&QA[(size_t)m*D128 + c] =
                make_float4(acc[rr][0]+pv.x, acc[rr][1]+pv.y, acc[rr][2]+pv.z, acc[rr][3]+pv.w);
        }
    }
}

// ---------------- sequential decode: 8 waves per batch elem, 2 barriers/step ----------------
// Finalize specialization: waves 0,6,7 compute argmax (wave0: bookkeeping+bc+action,
// wave6: QA prefetch lo, wave7: QA prefetch hi + shadow lse under the load latency).
// Waves 1-5 consume the bc broadcast after barrier C (~12 inst instead of ~90).
__global__ __attribute__((amdgpu_flat_work_group_size(TDEC, TDEC)))
void decode(
    const float* __restrict__ QA, const float* __restrict__ KVP,
    const float* __restrict__ wlast, const float* __restrict__ demand,
    const float* __restrict__ capv, const void* p_nd, const void* p_temp,
    int n_steps, float* __restrict__ out)
{
    __shared__ float sm[LDS_FLOATS];
    const int b = blockIdx.x, t = threadIdx.x;
    const int l = t & 63, g = t >> 6;          // lane, wave (= head = dim-block)
    const int qq = l >> 4, d16 = l & 15;       // PV mapping
    const int nd = read_scalar_int(p_nd);
    const float temp = read_scalar_float(p_temp);
    const float capfull = capv[0];
    float dyn = capv[b];
    const long mb = (long)b * NT;
    const bool hasB = (l < NT - 64);           // second-row validity (l < 37)
    const bool doF = (g == 0 || g >= 6);       // finalize waves

    // ---- K rows (head g) for n = l, l+64 ----
    float k0[16], k1[16];
    {
        const float* kr = KVP + (mb + l)*384 + g*16;
        #pragma unroll
        for (int j4 = 0; j4 < 4; ++j4){
            float4 a = *(const float4*)(kr + j4*4);
            k0[j4*4+0]=a.x; k0[j4*4+1]=a.y; k0[j4*4+2]=a.z; k0[j4*4+3]=a.w;
        }
    }
    if (hasB){
        const float* kr = KVP + (mb + l + 64)*384 + g*16;
        #pragma unroll
        for (int j4 = 0; j4 < 4; ++j4){
            float4 a = *(const float4*)(kr + j4*4);
            k1[j4*4+0]=a.x; k1[j4*4+1]=a.y; k1[j4*4+2]=a.z; k1[j4*4+3]=a.w;
        }
    } else {
        #pragma unroll
        for (int j = 0; j < 16; ++j) k1[j] = 0.f;
    }
    float kwl1 = 0.f, kwl2 = 0.f;
    #pragma unroll
    for (int j = 0; j < 16; ++j){
        float w = wlast[g*16 + j];
        kwl1 += w*k0[j]; kwl2 += w*k1[j];
    }
    // ---- kp2 rows (dims 16g..16g+16) for n = l, l+64 ----
    float p2a[16], p2b[16];
    {
        const float* kr = KVP + (mb + l)*384 + 256 + g*16;
        #pragma unroll
        for (int j4 = 0; j4 < 4; ++j4){
            float4 a = *(const float4*)(kr + j4*4);
            p2a[j4*4+0]=a.x; p2a[j4*4+1]=a.y; p2a[j4*4+2]=a.z; p2a[j4*4+3]=a.w;
        }
    }
    if (hasB){
        const float* kr = KVP + (mb + l + 64)*384 + 256 + g*16;
        #pragma unroll
        for (int j4 = 0; j4 < 4; ++j4){
            float4 a = *(const float4*)(kr + j4*4);
            p2b[j4*4+0]=a.x; p2b[j4*4+1]=a.y; p2b[j4*4+2]=a.z; p2b[j4*4+3]=a.w;
        }
    } else {
        #pragma unroll
        for (int j = 0; j < 16; ++j) p2b[j] = 0.f;
    }
    // ---- demand + mask registers (redundant across waves) ----
    float dem1 = demand[mb + l];
    float dem2 = hasB ? demand[mb + l + 64] : 0.f;
    float mk1a = 0.f, mk1b = 0.f;
    float m1 = (l < nd) ? 1.f : ((dem1 > dyn) ? 1.f : 0.f);
    float m2 = ((l + 64) < nd) ? 1.f : ((dem2 > dyn) ? 1.f : 0.f);
    int served = 0; float logps = 0.f;

    // ---- stage VH[g][n][d] (n zero-padded to 112), P pads, initial QV ----
    for (int i = t; i < 8*112*16; i += TDEC){
        int gg = i / 1792, r = i - gg*1792;
        int n = r >> 4, d = r & 15;
        sm[VH_OFF + gg*VGPP + n*VPITCH + d] =
            (n < NT) ? KVP[(mb + n)*384 + 128 + gg*16 + d] : 0.f;
    }
    for (int i = t; i < 8*PSTR; i += TDEC) sm[P_OFF + i] = 0.f;
    if (t >= 384) sm[QV_OFF + (t - 384)] = QA[mb*D128 + (t - 384)];
    __syncthreads();

    for (int s = 0; s < n_steps; ++s){
        // ==== P1: compat -> softmax -> PV (wave-internal, no barrier) ====
        float qk1 = 0.f, qk2 = 0.f;
        {
            const float4* qp = (const float4*)&sm[QV_OFF + g*16];
            #pragma unroll
            for (int j4 = 0; j4 < 4; ++j4){
                float4 q4 = qp[j4];
                qk1 += q4.x*k0[j4*4+0] + q4.y*k0[j4*4+1] + q4.z*k0[j4*4+2] + q4.w*k0[j4*4+3];
                qk2 += q4.x*k1[j4*4+0] + q4.y*k1[j4*4+1] + q4.z*k1[j4*4+2] + q4.w*k1[j4*4+3];
            }
        }
        float c1 = 0.25f*(qk1 + dyn*kwl1);
        if (m1 > 0.f) c1 = -1000000000.0f;
        float c2 = -1000000000.0f;
        if (hasB){
            float a = 0.25f*(qk2 + dyn*kwl2);
            c2 = (m2 > 0.f) ? -1000000000.0f : a;
        }
        float mx = wave_max64(fmaxf(c1, c2));
        float p1 = expf(c1 - mx);
        float p2v = hasB ? expf(c2 - mx) : 0.f;
        float ls = wave_sum64(p1 + p2v);
        sm[P_OFF + g*PSTR + l] = p1;
        if (hasB) sm[P_OFF + g*PSTR + 64 + l] = p2v;
        // same-wave DS ordering: write->read needs no __syncthreads
        float acc = 0.f;
        {
            const float4* pp = (const float4*)&sm[P_OFF + g*PSTR + qq*28];
            const float* vb = &sm[VH_OFF + g*VGPP + (qq*28)*VPITCH + d16];
            #pragma unroll
            for (int i4 = 0; i4 < 7; ++i4){
                float4 pv = pp[i4];
                acc += pv.x*vb[(i4*4+0)*VPITCH] + pv.y*vb[(i4*4+1)*VPITCH]
                     + pv.z*vb[(i4*4+2)*VPITCH] + pv.w*vb[(i4*4+3)*VPITCH];
            }
        }
        acc += __shfl_xor(acc, 16, 64);
        acc += __shfl_xor(acc, 32, 64);
        if (l < 16) sm[O_OFFS + g*16 + l] = acc / ls;

        // ==== P2: logit partials for dim-block g (own-wave O, no barrier) ====
        float lg1 = 0.f, lg2 = 0.f;
        {
            const float4* op = (const float4*)&sm[O_OFFS + g*16];
            #pragma unroll
            for (int j4 = 0; j4 < 4; ++j4){
                float4 o4 = op[j4];
                lg1 += o4.x*p2a[j4*4+0] + o4.y*p2a[j4*4+1] + o4.z*p2a[j4*4+2] + o4.w*p2a[j4*4+3];
                lg2 += o4.x*p2b[j4*4+0] + o4.y*p2b[j4*4+1] + o4.z*p2b[j4*4+2] + o4.w*p2b[j4*4+3];
            }
        }
        sm[LGH_OFF + g*104 + l] = lg1;
        if (hasB) sm[LGH_OFF + g*104 + 64 + l] = lg2;
        __syncthreads();                                   // B

        if (doF){
            // ==== F (waves 0,6,7): raw-score argmax (tanh monotone -> same winner) ====
            float s1v = 0.f;
            #pragma unroll
            for (int w = 0; w < 8; ++w) s1v += sm[LGH_OFF + w*104 + l];
            float s2v = 0.f;
            if (hasB){
                #pragma unroll
                for (int w = 0; w < 8; ++w) s2v += sm[LGH_OFF + w*104 + 64 + l];
            }
            float r1 = (m1 > 0.f) ? -3.0e38f : s1v;
            float r2 = hasB ? ((m2 > 0.f) ? -3.0e38f : s2v) : -3.3e38f;
            float bv = r1; int bix = l;
            if (r2 > bv){ bv = r2; bix = l + 64; }
            wave_argmax64(bv, bix);
            // QA row fetch for next step (waves 6,7): issue immediately
            float qreg = 0.f;
            if (g >= 6) qreg = QA[(mb + bix)*D128 + (g - 6)*64 + l];
            // save pre-update state for wave7's shadow lse
            float m1o = m1, m2o = m2;
            bool keep_lp = (served < NT - 1);
            // bookkeeping (wave-uniform, redundant across 0,6,7)
            float selv = (bix < 64) ? __shfl(dem1, bix, 64) : __shfl(dem2, bix - 64, 64);
            float vis  = (bix < 64) ? __shfl(mk1a, bix, 64) : __shfl(mk1b, bix - 64, 64);
            bool go = bix < nd;
            float dynN = go ? capfull : (dyn - selv);
            if (!go && vis == 0.f) served++;
            if (bix == l && l >= nd) mk1a = 1.f;
            if (hasB && bix == (l + 64)) mk1b = 1.f;
            bool done = served >= NT - nd;
            float depotf = (go && !done) ? 1.f : 0.f;
            dyn = dynN;
            m1 = fmaxf(mk1a, (dem1 > dyn) ? 1.f : 0.f);
            if (l < nd) m1 = depotf;
            m2 = fmaxf(mk1b, (dem2 > dyn) ? 1.f : 0.f);
            if ((l + 64) < nd) m2 = depotf;
            if (g == 0){
                if (l == 0){
                    *(float4*)&sm[BC_OFF] = make_float4(dynN, depotf, (float)bix, 0.f);
                    out[(size_t)b*n_steps + s] = (float)bix;
                }
            } else if (g == 7){
                // shadow lse under the QA load latency
                float Lm = tanhf(bv * INV_D_CONST) * 10.0f / temp;
                float L1 = (m1o > 0.f) ? (-1000000000.0f / temp)
                                       : (tanhf(s1v * INV_D_CONST) * 10.0f / temp);
                float e1 = expf(L1 - Lm);
                float e2 = 0.f;
                if (hasB){
                    float L2 = (m2o > 0.f) ? (-1000000000.0f / temp)
                                           : (tanhf(s2v * INV_D_CONST) * 10.0f / temp);
                    e2 = expf(L2 - Lm);
                }
                float ss = wave_sum64(e1 + e2);
                if (keep_lp) logps += -logf(ss);
            }
            if (g >= 6) sm[QV_OFF + (g - 6)*64 + l] = qreg;
        }
        __syncthreads();                                   // C

        // ==== waves 1-5: consume broadcast, update register state (VALU only) ====
        if (!doF){
            float4 bc = *(const float4*)&sm[BC_OFF];
            dyn = bc.x;
            float depotf = bc.y;
            int idxu = (int)bc.z;
            if (idxu == l && l >= nd) mk1a = 1.f;
            if (hasB && idxu == (l + 64)) mk1b = 1.f;
            m1 = fmaxf(mk1a, (dem1 > dyn) ? 1.f : 0.f);
            if (l < nd) m1 = depotf;
            m2 = fmaxf(mk1b, (dem2 > dyn) ? 1.f : 0.f);
            if ((l + 64) < nd) m2 = depotf;
        }
    }
    if (g == 7 && l == 0) out[(size_t)gridDim.x*n_steps + b] = logps;
}

extern "C" void kernel_launch(void* const* d_in, const int* in_sizes, int n_in,
                              void* d_out, int out_size, void* d_ws, size_t ws_size,
                              hipStream_t stream) {
    const float* enc     = (const float*)d_in[0];
    const float* pool    = (const float*)d_in[1];
    const float* capv    = (const float*)d_in[2];
    const float* demand  = (const float*)d_in[3];
    const float* fc_w    = (const float*)d_in[4];
    const float* fc1_w   = (const float*)d_in[5];
    const float* attn_w  = (const float*)d_in[6];
    const float* attn_k  = (const float*)d_in[7];
    const float* attn_v  = (const float*)d_in[8];
    const float* attn_fc = (const float*)d_in[9];
    const float* prob_k  = (const float*)d_in[10];
    const void*  p_nd    = d_in[12];
    const void*  p_temp  = d_in[13];

    int B = in_sizes[1] / D128;          // pool is (B, D)
    int n_steps = out_size / B - 1;      // out = B*n_steps actions + B logps
    int M = B * NT;

    float* ws    = (float*)d_ws;
    float* Wcat  = ws;                               // 128*512
    float* wlast = Wcat + 128*512;                   // 128
    float* pq    = wlast + 128;                      // B*128
    float* KVP   = pq + (size_t)B*D128;              // M*384
    float* QA    = KVP + (size_t)M*384;              // M*128

    prep_w2<<<129, 512, 0, stream>>>(fc_w, attn_w, prob_k, attn_fc, attn_k, attn_v, Wcat, wlast);
    prep_pq<<<B, 128, 0, stream>>>(pool, fc1_w, attn_w, pq);
    dim3 ggrid((M + 63)/64, 8);
    gemm_prep<<<ggrid, 256, 0, stream>>>(enc, Wcat, pq, M, KVP, QA);

    decode<<<B, TDEC, 0, stream>>>(QA, KVP, wlast, demand, capv, p_nd, p_temp,
                                   n_steps, (float*)d_out);
}

// Round 10
// 1469.568 us; speedup vs baseline: 1.2572x; 1.2572x over previous
//
#include <hip/hip_runtime.h>

#define D128 128
#define NT 101
#define TDEC 512
#define PSTR 112            // padded p row: 4 quarters of 28 floats (16B aligned)
#define PVP 116             // VH inner (n) pitch, mult of 4 -> aligned b128
#define VGPP (16*PVP)       // per-head VH pitch = 1856 floats
#define LGP 208             // packed LGH pitch: [w][2l]=lg1, [2l+1]=lg2

// ---- decode LDS layout (floats) ----
#define VH_OFF   0                       // [8][16 d][PVP n] V slices (n zero-padded)
#define P_OFF    (VH_OFF + 8*VGPP)       // 8 x PSTR
#define LGH_OFF  (P_OFF + 8*PSTR)        // 8 x LGP packed logit partials
#define O_OFFS   (LGH_OFF + 8*LGP)       // 128
#define QV_OFF   (O_OFFS + 128)          // 128  raw QA row of current selection
#define LDS_FLOATS (QV_OFF + 128)        // 17664 floats = 70,656 B -> 2 WG/CU

#define INV_D_CONST 0.08838834764831845f
#define NEG_INF __int_as_float(0xff800000)

__device__ __forceinline__ int read_scalar_int(const void* p){
    unsigned u = *(const unsigned*)p;
    if (u < 1000000u) return (int)u;
    return (int)__uint_as_float(u);
}
__device__ __forceinline__ float read_scalar_float(const void* p){
    unsigned u = *(const unsigned*)p;
    if (u < 1000000u) return (float)(int)u;
    return __uint_as_float(u);
}

// ---- DPP cross-lane helpers (VALU pipe, no DS) ----
template<int C> __device__ __forceinline__ float dppf(float x){
    return __int_as_float(__builtin_amdgcn_update_dpp(
        __float_as_int(x), __float_as_int(x), C, 0xF, 0xF, false));
}
template<int C> __device__ __forceinline__ int dppi(int x){
    return __builtin_amdgcn_update_dpp(x, x, C, 0xF, 0xF, false);
}
// masked DPP with explicit identity for non-selected rows
template<int C, int RM> __device__ __forceinline__ float dppmf(float idv, float x){
    return __int_as_float(__builtin_amdgcn_update_dpp(
        __float_as_int(idv), __float_as_int(x), C, RM, 0xF, false));
}
template<int C, int RM> __device__ __forceinline__ int dppmi(int idv, int x){
    return __builtin_amdgcn_update_dpp(idv, x, C, RM, 0xF, false);
}
__device__ __forceinline__ float rdlf(float v, int lane){
    return __int_as_float(__builtin_amdgcn_readlane(__float_as_int(v), lane));
}
// Canonical wave64 reduction: 4 mirror stages make each 16-lane row uniform,
// then row_bcast15 (mask 0xa) and row_bcast31 (mask 0x8) merge rows into row 3.
// Valid ONLY because rows are uniform when the bcast stages run.
__device__ __forceinline__ float wave_sum64(float v){
    v += dppf<0xB1>(v); v += dppf<0x4E>(v); v += dppf<0x141>(v); v += dppf<0x140>(v);
    v += dppmf<0x142,0xa>(0.f, v);          // row1 += row0, row3 += row2
    v += dppmf<0x143,0x8>(0.f, v);          // row3 += (row0+row1)
    return rdlf(v, 63);
}
__device__ __forceinline__ float wave_max64(float v){
    v = fmaxf(v, dppf<0xB1>(v)); v = fmaxf(v, dppf<0x4E>(v));
    v = fmaxf(v, dppf<0x141>(v)); v = fmaxf(v, dppf<0x140>(v));
    v = fmaxf(v, dppmf<0x142,0xa>(NEG_INF, v));
    v = fmaxf(v, dppmf<0x143,0x8>(NEG_INF, v));
    return rdlf(v, 63);
}
__device__ __forceinline__ void wave_argmax64(float& v, int& i){
    { float ov = dppf<0xB1>(v);  int oi = dppi<0xB1>(i);  if (ov>v || (ov==v && oi<i)){v=ov;i=oi;} }
    { float ov = dppf<0x4E>(v);  int oi = dppi<0x4E>(i);  if (ov>v || (ov==v && oi<i)){v=ov;i=oi;} }
    { float ov = dppf<0x141>(v); int oi = dppi<0x141>(i); if (ov>v || (ov==v && oi<i)){v=ov;i=oi;} }
    { float ov = dppf<0x140>(v); int oi = dppi<0x140>(i); if (ov>v || (ov==v && oi<i)){v=ov;i=oi;} }
    { float ov = dppmf<0x142,0xa>(NEG_INF, v); int oi = dppmi<0x142,0xa>(0, i);
      if (ov>v || (ov==v && oi<i)){v=ov;i=oi;} }
    { float ov = dppmf<0x143,0x8>(NEG_INF, v); int oi = dppmi<0x143,0x8>(0, i);
      if (ov>v || (ov==v && oi<i)){v=ov;i=oi;} }
    v = rdlf(v, 63);
    i = __builtin_amdgcn_readlane(i, 63);
}

// ---------------- weight folding (unchanged) ----------------
__global__ __launch_bounds__(512) void prep_w2(
        const float* __restrict__ fc_w, const float* __restrict__ attn_w,
        const float* __restrict__ prob_k, const float* __restrict__ attn_fc,
        const float* __restrict__ attn_k, const float* __restrict__ attn_v,
        float* __restrict__ Wcat, float* __restrict__ wlast){
    int i = blockIdx.x, t = threadIdx.x;
    if (i < 128){
        if (t < 128){
            Wcat[i*512 + t] = attn_k[i*D128 + t];
        } else if (t < 256){
            int j = t - 128;
            Wcat[i*512 + 128 + j] = attn_v[i*D128 + j];
        } else if (t < 384){
            int j = t - 256; float acc = 0.f;
            for (int e = 0; e < D128; ++e) acc += prob_k[i*D128+e]*attn_fc[j*D128+e];
            Wcat[i*512 + 256 + j] = acc;
        } else {
            int j = t - 384; float acc = 0.f;
            for (int e = 0; e < D128; ++e) acc += fc_w[i*D128+e]*attn_w[e*D128+j];
            Wcat[i*512 + 384 + j] = acc;
        }
    } else if (t < 128){
        float acc = 0.f;
        for (int e = 0; e < D128; ++e) acc += fc_w[128*D128+e]*attn_w[e*D128+t];
        wlast[t] = acc;
    }
}

__global__ __launch_bounds__(128) void prep_pq(
        const float* __restrict__ pool, const float* __restrict__ fc1_w,
        const float* __restrict__ attn_w, float* __restrict__ pq){
    __shared__ float s1[128], s2[128];
    int b = blockIdx.x, t = threadIdx.x;
    s1[t] = pool[(size_t)b*D128 + t];
    __syncthreads();
    float a = 0.f;
    for (int i = 0; i < D128; ++i) a += s1[i]*fc1_w[i*D128 + t];
    s2[t] = a;
    __syncthreads();
    float a2 = 0.f;
    for (int i = 0; i < D128; ++i) a2 += s2[i]*attn_w[i*D128 + t];
    pq[(size_t)b*D128 + t] = a2;
}

__global__ __launch_bounds__(256) void gemm_prep(
        const float* __restrict__ enc, const float* __restrict__ Wcat,
        const float* __restrict__ pq, int M,
        float* __restrict__ KVP, float* __restrict__ QA){
    __shared__ float As[64*132];
    const int t = threadIdx.x;
    const int m0 = blockIdx.x * 64;
    const int cb0 = blockIdx.y * 64;
    for (int i = t; i < 64*32; i += 256){
        int row = i >> 5, c4 = (i & 31) << 2;
        float4 val = make_float4(0.f,0.f,0.f,0.f);
        if (m0 + row < M) val = *(const float4*)(enc + (size_t)(m0+row)*D128 + c4);
        *(float4*)&As[row*132 + c4] = val;
    }
    __syncthreads();
    const int tx = t & 15, ty = t >> 4;
    float acc[4][4];
    #pragma unroll
    for (int i = 0; i < 4; ++i)
        #pragma unroll
        for (int j = 0; j < 4; ++j) acc[i][j] = 0.f;
    const float* wp = Wcat + cb0 + tx*4;
    #pragma unroll 4
    for (int k = 0; k < 128; ++k){
        float4 bv = *(const float4*)(wp + (size_t)k*512);
        float a0 = As[(ty*4+0)*132 + k];
        float a1 = As[(ty*4+1)*132 + k];
        float a2 = As[(ty*4+2)*132 + k];
        float a3 = As[(ty*4+3)*132 + k];
        acc[0][0] += a0*bv.x; acc[0][1] += a0*bv.y; acc[0][2] += a0*bv.z; acc[0][3] += a0*bv.w;
        acc[1][0] += a1*bv.x; acc[1][1] += a1*bv.y; acc[1][2] += a1*bv.z; acc[1][3] += a1*bv.w;
        acc[2][0] += a2*bv.x; acc[2][1] += a2*bv.y; acc[2][2] += a2*bv.z; acc[2][3] += a2*bv.w;
        acc[3][0] += a3*bv.x; acc[3][1] += a3*bv.y; acc[3][2] += a3*bv.z; acc[3][3] += a3*bv.w;
    }
    #pragma unroll
    for (int rr = 0; rr < 4; ++rr){
        int m = m0 + ty*4 + rr;
        if (m >= M) continue;
        if (cb0 < 384){
            *(float4*)&KVP[(size_t)m*384 + cb0 + tx*4] =
                make_float4(acc[rr][0], acc[rr][1], acc[rr][2], acc[rr][3]);
        } else {
            int bb = m / NT;
            int c = cb0 - 384 + tx*4;
            float4 pv = *(const float4*)(pq + (size_t)bb*D128 + c);
            *(float4*)&QA[(size_t)m*D128 + c] =
                make_float4(acc[rr][0]+pv.x, acc[rr][1]+pv.y, acc[rr][2]+pv.z, acc[rr][3]+pv.w);
        }
    }
}

// ---------------- sequential decode: 8 waves per batch elem, 2 barriers/step ----------------
// Uniform code path (VGPR must stay 64 -> 2 WG/CU). DS-pipe diet: V transposed for
// b128 reads, full-wave reductions DPP+readlane (VALU), LGH packed float2,
// bookkeeping via readlane. PV cross-quarter reduce MUST be shfl_xor (element-wise
// cross-row; DPP row_bcast is scalar-per-row and silently wrong there — R9 bug).
__global__ __attribute__((amdgpu_flat_work_group_size(TDEC, TDEC)))
void decode(
    const float* __restrict__ QA, const float* __restrict__ KVP,
    const float* __restrict__ wlast, const float* __restrict__ demand,
    const float* __restrict__ capv, const void* p_nd, const void* p_temp,
    int n_steps, float* __restrict__ out)
{
    __shared__ float sm[LDS_FLOATS];
    const int b = blockIdx.x, t = threadIdx.x;
    const int l = t & 63, g = t >> 6;          // lane, wave (= head = dim-block)
    const int qq = l >> 4, d16 = l & 15;       // PV mapping
    const int nd = read_scalar_int(p_nd);
    const float temp = read_scalar_float(p_temp);
    const float capfull = capv[0];
    float dyn = capv[b];
    const long mb = (long)b * NT;
    const bool hasB = (l < NT - 64);           // second-row validity (l < 37)

    // ---- K rows (head g) for n = l, l+64 ----
    float k0[16], k1[16];
    {
        const float* kr = KVP + (mb + l)*384 + g*16;
        #pragma unroll
        for (int j4 = 0; j4 < 4; ++j4){
            float4 a = *(const float4*)(kr + j4*4);
            k0[j4*4+0]=a.x; k0[j4*4+1]=a.y; k0[j4*4+2]=a.z; k0[j4*4+3]=a.w;
        }
    }
    if (hasB){
        const float* kr = KVP + (mb + l + 64)*384 + g*16;
        #pragma unroll
        for (int j4 = 0; j4 < 4; ++j4){
            float4 a = *(const float4*)(kr + j4*4);
            k1[j4*4+0]=a.x; k1[j4*4+1]=a.y; k1[j4*4+2]=a.z; k1[j4*4+3]=a.w;
        }
    } else {
        #pragma unroll
        for (int j = 0; j < 16; ++j) k1[j] = 0.f;
    }
    float kwl1 = 0.f, kwl2 = 0.f;
    #pragma unroll
    for (int j = 0; j < 16; ++j){
        float w = wlast[g*16 + j];
        kwl1 += w*k0[j]; kwl2 += w*k1[j];
    }
    // ---- kp2 rows (dims 16g..16g+16) for n = l, l+64 ----
    float p2a[16], p2b[16];
    {
        const float* kr = KVP + (mb + l)*384 + 256 + g*16;
        #pragma unroll
        for (int j4 = 0; j4 < 4; ++j4){
            float4 a = *(const float4*)(kr + j4*4);
            p2a[j4*4+0]=a.x; p2a[j4*4+1]=a.y; p2a[j4*4+2]=a.z; p2a[j4*4+3]=a.w;
        }
    }
    if (hasB){
        const float* kr = KVP + (mb + l + 64)*384 + 256 + g*16;
        #pragma unroll
        for (int j4 = 0; j4 < 4; ++j4){
            float4 a = *(const float4*)(kr + j4*4);
            p2b[j4*4+0]=a.x; p2b[j4*4+1]=a.y; p2b[j4*4+2]=a.z; p2b[j4*4+3]=a.w;
        }
    } else {
        #pragma unroll
        for (int j = 0; j < 16; ++j) p2b[j] = 0.f;
    }
    // ---- demand + mask registers (redundant across waves) ----
    float dem1 = demand[mb + l];
    float dem2 = hasB ? demand[mb + l + 64] : 0.f;
    float mk1a = 0.f, mk1b = 0.f;
    float m1 = (l < nd) ? 1.f : ((dem1 > dyn) ? 1.f : 0.f);
    float m2 = ((l + 64) < nd) ? 1.f : ((dem2 > dyn) ? 1.f : 0.f);
    int served = 0; float logps = 0.f;

    // ---- stage VH[g][d][n] transposed (n zero-padded to PVP), P pads, initial QV ----
    for (int i = t; i < 8*112*16; i += TDEC){
        int gg = i / 1792, r = i - gg*1792;
        int n = r >> 4, d = r & 15;            // d inner: coalesced global read
        sm[VH_OFF + gg*VGPP + d*PVP + n] =
            (n < NT) ? KVP[(mb + n)*384 + 128 + gg*16 + d] : 0.f;
    }
    for (int i = t; i < 8*PSTR; i += TDEC) sm[P_OFF + i] = 0.f;
    if (t >= 384) sm[QV_OFF + (t - 384)] = QA[mb*D128 + (t - 384)];
    __syncthreads();

    for (int s = 0; s < n_steps; ++s){
        // ==== P1: compat -> softmax -> PV (wave-internal, no barrier) ====
        float qk1 = 0.f, qk2 = 0.f;
        {
            const float4* qp = (const float4*)&sm[QV_OFF + g*16];
            #pragma unroll
            for (int j4 = 0; j4 < 4; ++j4){
                float4 q4 = qp[j4];
                qk1 += q4.x*k0[j4*4+0] + q4.y*k0[j4*4+1] + q4.z*k0[j4*4+2] + q4.w*k0[j4*4+3];
                qk2 += q4.x*k1[j4*4+0] + q4.y*k1[j4*4+1] + q4.z*k1[j4*4+2] + q4.w*k1[j4*4+3];
            }
        }
        float c1 = 0.25f*(qk1 + dyn*kwl1);
        if (m1 > 0.f) c1 = -1000000000.0f;
        float c2 = -1000000000.0f;
        if (hasB){
            float a = 0.25f*(qk2 + dyn*kwl2);
            c2 = (m2 > 0.f) ? -1000000000.0f : a;
        }
        float mx = wave_max64(fmaxf(c1, c2));
        float p1 = expf(c1 - mx);
        float p2v = hasB ? expf(c2 - mx) : 0.f;
        float ls = wave_sum64(p1 + p2v);
        sm[P_OFF + g*PSTR + l] = p1;
        if (hasB) sm[P_OFF + g*PSTR + 64 + l] = p2v;
        // same-wave DS ordering: write->read needs no __syncthreads
        float acc = 0.f;
        {
            const float4* pp = (const float4*)&sm[P_OFF + g*PSTR + qq*28];
            const float4* vp = (const float4*)&sm[VH_OFF + g*VGPP + d16*PVP + qq*28];
            #pragma unroll
            for (int i4 = 0; i4 < 7; ++i4){
                float4 pv = pp[i4];
                float4 vv = vp[i4];
                acc += pv.x*vv.x + pv.y*vv.y + pv.z*vv.z + pv.w*vv.w;
            }
        }
        // element-wise cross-row reduce: MUST use permute network (not DPP bcast)
        acc += __shfl_xor(acc, 16, 64);
        acc += __shfl_xor(acc, 32, 64);
        if (l < 16) sm[O_OFFS + g*16 + l] = acc / ls;

        // ==== P2: logit partials for dim-block g (own-wave O, no barrier) ====
        float lg1 = 0.f, lg2 = 0.f;
        {
            const float4* op = (const float4*)&sm[O_OFFS + g*16];
            #pragma unroll
            for (int j4 = 0; j4 < 4; ++j4){
                float4 o4 = op[j4];
                lg1 += o4.x*p2a[j4*4+0] + o4.y*p2a[j4*4+1] + o4.z*p2a[j4*4+2] + o4.w*p2a[j4*4+3];
                lg2 += o4.x*p2b[j4*4+0] + o4.y*p2b[j4*4+1] + o4.z*p2b[j4*4+2] + o4.w*p2b[j4*4+3];
            }
        }
        if (hasB) *(float2*)&sm[LGH_OFF + g*LGP + 2*l] = make_float2(lg1, lg2);
        else      sm[LGH_OFF + g*LGP + 2*l] = lg1;
        __syncthreads();                                   // B

        // ==== F: raw-score argmax (tanh monotone -> same winner), redundant per wave ====
        float s1v = 0.f, s2v = 0.f;
        #pragma unroll
        for (int w = 0; w < 8; ++w){
            float2 lp = *(const float2*)&sm[LGH_OFF + w*LGP + 2*l];
            s1v += lp.x; s2v += lp.y;      // s2v garbage when !hasB (unused)
        }
        float r1 = (m1 > 0.f) ? -3.0e38f : s1v;
        float r2 = hasB ? ((m2 > 0.f) ? -3.0e38f : s2v) : -3.3e38f;
        float bv = r1; int bix = l;
        if (r2 > bv){ bv = r2; bix = l + 64; }
        wave_argmax64(bv, bix);
        // QA row fetch for next step (waves 6,7): issue immediately
        float qreg = 0.f;
        if (t >= 384) qreg = QA[(mb + bix)*D128 + (t - 384)];
        // save pre-update state for wave0's shadow lse
        float m1o = m1, m2o = m2;
        bool keep_lp = (served < NT - 1);
        // bookkeeping (wave-uniform; readlane, no DS)
        float selv = (bix < 64) ? rdlf(dem1, bix) : rdlf(dem2, bix - 64);
        float vis  = (bix < 64) ? rdlf(mk1a, bix) : rdlf(mk1b, bix - 64);
        bool go = bix < nd;
        float dynN = go ? capfull : (dyn - selv);
        if (!go && vis == 0.f) served++;
        if (bix == l && l >= nd) mk1a = 1.f;
        if (hasB && bix == (l + 64)) mk1b = 1.f;
        bool done = served >= NT - nd;
        float depotf = (go && !done) ? 1.f : 0.f;
        dyn = dynN;
        m1 = fmaxf(mk1a, (dem1 > dyn) ? 1.f : 0.f);
        if (l < nd) m1 = depotf;
        m2 = fmaxf(mk1b, (dem2 > dyn) ? 1.f : 0.f);
        if ((l + 64) < nd) m2 = depotf;
        if (t >= 384) sm[QV_OFF + (t - 384)] = qreg;
        if (g == 0 && l == 0) out[(size_t)b*n_steps + s] = (float)bix;
        __syncthreads();                                   // C

        // ==== wave 0 shadow: true logits -> lse -> logp (hidden under other waves' P1) ====
        if (g == 0){
            float Lm = tanhf(bv * INV_D_CONST) * 10.0f / temp;
            float L1 = (m1o > 0.f) ? (-1000000000.0f / temp)
                                   : (tanhf(s1v * INV_D_CONST) * 10.0f / temp);
            float e1 = expf(L1 - Lm);
            float e2 = 0.f;
            if (hasB){
                float L2 = (m2o > 0.f) ? (-1000000000.0f / temp)
                                       : (tanhf(s2v * INV_D_CONST) * 10.0f / temp);
                e2 = expf(L2 - Lm);
            }
            float ss = wave_sum64(e1 + e2);
            if (keep_lp) logps += -logf(ss);
        }
    }
    if (t == 0) out[(size_t)gridDim.x*n_steps + b] = logps;
}

extern "C" void kernel_launch(void* const* d_in, const int* in_sizes, int n_in,
                              void* d_out, int out_size, void* d_ws, size_t ws_size,
                              hipStream_t stream) {
    const float* enc     = (const float*)d_in[0];
    const float* pool    = (const float*)d_in[1];
    const float* capv    = (const float*)d_in[2];
    const float* demand  = (const float*)d_in[3];
    const float* fc_w    = (const float*)d_in[4];
    const float* fc1_w   = (const float*)d_in[5];
    const float* attn_w  = (const float*)d_in[6];
    const float* attn_k  = (const float*)d_in[7];
    const float* attn_v  = (const float*)d_in[8];
    const float* attn_fc = (const float*)d_in[9];
    const float* prob_k  = (const float*)d_in[10];
    const void*  p_nd    = d_in[12];
    const void*  p_temp  = d_in[13];

    int B = in_sizes[1] / D128;          // pool is (B, D)
    int n_steps = out_size / B - 1;      // out = B*n_steps actions + B logps
    int M = B * NT;

    float* ws    = (float*)d_ws;
    float* Wcat  = ws;                               // 128*512
    float* wlast = Wcat + 128*512;                   // 128
    float* pq    = wlast + 128;                      // B*128
    float* KVP   = pq + (size_t)B*D128;              // M*384
    float* QA    = KVP + (size_t)M*384;              // M*128

    prep_w2<<<129, 512, 0, stream>>>(fc_w, attn_w, prob_k, attn_fc, attn_k, attn_v, Wcat, wlast);
    prep_pq<<<B, 128, 0, stream>>>(pool, fc1_w, attn_w, pq);
    dim3 ggrid((M + 63)/64, 8);
    gemm_prep<<<ggrid, 256, 0, stream>>>(enc, Wcat, pq, M, KVP, QA);

    decode<<<B, TDEC, 0, stream>>>(QA, KVP, wlast, demand, capv, p_nd, p_temp,
                                   n_steps, (float*)d_out);
}

// Round 11
// 1076.858 us; speedup vs baseline: 1.7157x; 1.3647x over previous
//
#include <hip/hip_runtime.h>

#define D128 128
#define NT 101
#define TDEC 512
#define PSTR 112            // padded p row: 4 quarters of 28 floats (16B aligned)
#define PVP 116             // VH inner (n) pitch, mult of 4 -> aligned b128
#define VGPP (16*PVP)       // per-head VH pitch = 1856 floats
#define LGB 832             // one LGH buffer: 8 waves x 104

// ---- decode LDS layout (floats) ----
#define VH_OFF   0                       // [8][16 d][PVP n] V slices (n zero-padded)
#define P_OFF    (VH_OFF + 8*VGPP)       // 8 x PSTR
#define LGH_OFF  (P_OFF + 8*PSTR)        // 2 x 8 x 104 double-buffered logit partials
#define LDS_FLOATS (LGH_OFF + 2*LGB)     // 17408 floats = 69,632 B -> 2 WG/CU

#define INV_D_CONST 0.08838834764831845f
#define NEG_INF __int_as_float(0xff800000)

__device__ __forceinline__ int read_scalar_int(const void* p){
    unsigned u = *(const unsigned*)p;
    if (u < 1000000u) return (int)u;
    return (int)__uint_as_float(u);
}
__device__ __forceinline__ float read_scalar_float(const void* p){
    unsigned u = *(const unsigned*)p;
    if (u < 1000000u) return (float)(int)u;
    return __uint_as_float(u);
}

// ---- DPP cross-lane helpers (VALU pipe, no DS) — verified correct in R10 ----
template<int C> __device__ __forceinline__ float dppf(float x){
    return __int_as_float(__builtin_amdgcn_update_dpp(
        __float_as_int(x), __float_as_int(x), C, 0xF, 0xF, false));
}
template<int C> __device__ __forceinline__ int dppi(int x){
    return __builtin_amdgcn_update_dpp(x, x, C, 0xF, 0xF, false);
}
template<int C, int RM> __device__ __forceinline__ float dppmf(float idv, float x){
    return __int_as_float(__builtin_amdgcn_update_dpp(
        __float_as_int(idv), __float_as_int(x), C, RM, 0xF, false));
}
template<int C, int RM> __device__ __forceinline__ int dppmi(int idv, int x){
    return __builtin_amdgcn_update_dpp(idv, x, C, RM, 0xF, false);
}
__device__ __forceinline__ float rdlf(float v, int lane){
    return __int_as_float(__builtin_amdgcn_readlane(__float_as_int(v), lane));
}
// Canonical wave64 reductions: 4 mirror stages (rows uniform), bcast15/31 merge.
__device__ __forceinline__ float wave_sum64(float v){
    v += dppf<0xB1>(v); v += dppf<0x4E>(v); v += dppf<0x141>(v); v += dppf<0x140>(v);
    v += dppmf<0x142,0xa>(0.f, v);
    v += dppmf<0x143,0x8>(0.f, v);
    return rdlf(v, 63);
}
__device__ __forceinline__ float wave_max64(float v){
    v = fmaxf(v, dppf<0xB1>(v)); v = fmaxf(v, dppf<0x4E>(v));
    v = fmaxf(v, dppf<0x141>(v)); v = fmaxf(v, dppf<0x140>(v));
    v = fmaxf(v, dppmf<0x142,0xa>(NEG_INF, v));
    v = fmaxf(v, dppmf<0x143,0x8>(NEG_INF, v));
    return rdlf(v, 63);
}
__device__ __forceinline__ void wave_argmax64(float& v, int& i){
    { float ov = dppf<0xB1>(v);  int oi = dppi<0xB1>(i);  if (ov>v || (ov==v && oi<i)){v=ov;i=oi;} }
    { float ov = dppf<0x4E>(v);  int oi = dppi<0x4E>(i);  if (ov>v || (ov==v && oi<i)){v=ov;i=oi;} }
    { float ov = dppf<0x141>(v); int oi = dppi<0x141>(i); if (ov>v || (ov==v && oi<i)){v=ov;i=oi;} }
    { float ov = dppf<0x140>(v); int oi = dppi<0x140>(i); if (ov>v || (ov==v && oi<i)){v=ov;i=oi;} }
    { float ov = dppmf<0x142,0xa>(NEG_INF, v); int oi = dppmi<0x142,0xa>(0, i);
      if (ov>v || (ov==v && oi<i)){v=ov;i=oi;} }
    { float ov = dppmf<0x143,0x8>(NEG_INF, v); int oi = dppmi<0x143,0x8>(0, i);
      if (ov>v || (ov==v && oi<i)){v=ov;i=oi;} }
    v = rdlf(v, 63);
    i = __builtin_amdgcn_readlane(i, 63);
}

// ---------------- weight folding (unchanged) ----------------
__global__ __launch_bounds__(512) void prep_w2(
        const float* __restrict__ fc_w, const float* __restrict__ attn_w,
        const float* __restrict__ prob_k, const float* __restrict__ attn_fc,
        const float* __restrict__ attn_k, const float* __restrict__ attn_v,
        float* __restrict__ Wcat, float* __restrict__ wlast){
    int i = blockIdx.x, t = threadIdx.x;
    if (i < 128){
        if (t < 128){
            Wcat[i*512 + t] = attn_k[i*D128 + t];
        } else if (t < 256){
            int j = t - 128;
            Wcat[i*512 + 128 + j] = attn_v[i*D128 + j];
        } else if (t < 384){
            int j = t - 256; float acc = 0.f;
            for (int e = 0; e < D128; ++e) acc += prob_k[i*D128+e]*attn_fc[j*D128+e];
            Wcat[i*512 + 256 + j] = acc;
        } else {
            int j = t - 384; float acc = 0.f;
            for (int e = 0; e < D128; ++e) acc += fc_w[i*D128+e]*attn_w[e*D128+j];
            Wcat[i*512 + 384 + j] = acc;
        }
    } else if (t < 128){
        float acc = 0.f;
        for (int e = 0; e < D128; ++e) acc += fc_w[128*D128+e]*attn_w[e*D128+t];
        wlast[t] = acc;
    }
}

__global__ __launch_bounds__(128) void prep_pq(
        const float* __restrict__ pool, const float* __restrict__ fc1_w,
        const float* __restrict__ attn_w, float* __restrict__ pq){
    __shared__ float s1[128], s2[128];
    int b = blockIdx.x, t = threadIdx.x;
    s1[t] = pool[(size_t)b*D128 + t];
    __syncthreads();
    float a = 0.f;
    for (int i = 0; i < D128; ++i) a += s1[i]*fc1_w[i*D128 + t];
    s2[t] = a;
    __syncthreads();
    float a2 = 0.f;
    for (int i = 0; i < D128; ++i) a2 += s2[i]*attn_w[i*D128 + t];
    pq[(size_t)b*D128 + t] = a2;
}

__global__ __launch_bounds__(256) void gemm_prep(
        const float* __restrict__ enc, const float* __restrict__ Wcat,
        const float* __restrict__ pq, int M,
        float* __restrict__ KVP, float* __restrict__ QA){
    __shared__ float As[64*132];
    const int t = threadIdx.x;
    const int m0 = blockIdx.x * 64;
    const int cb0 = blockIdx.y * 64;
    for (int i = t; i < 64*32; i += 256){
        int row = i >> 5, c4 = (i & 31) << 2;
        float4 val = make_float4(0.f,0.f,0.f,0.f);
        if (m0 + row < M) val = *(const float4*)(enc + (size_t)(m0+row)*D128 + c4);
        *(float4*)&As[row*132 + c4] = val;
    }
    __syncthreads();
    const int tx = t & 15, ty = t >> 4;
    float acc[4][4];
    #pragma unroll
    for (int i = 0; i < 4; ++i)
        #pragma unroll
        for (int j = 0; j < 4; ++j) acc[i][j] = 0.f;
    const float* wp = Wcat + cb0 + tx*4;
    #pragma unroll 4
    for (int k = 0; k < 128; ++k){
        float4 bv = *(const float4*)(wp + (size_t)k*512);
        float a0 = As[(ty*4+0)*132 + k];
        float a1 = As[(ty*4+1)*132 + k];
        float a2 = As[(ty*4+2)*132 + k];
        float a3 = As[(ty*4+3)*132 + k];
        acc[0][0] += a0*bv.x; acc[0][1] += a0*bv.y; acc[0][2] += a0*bv.z; acc[0][3] += a0*bv.w;
        acc[1][0] += a1*bv.x; acc[1][1] += a1*bv.y; acc[1][2] += a1*bv.z; acc[1][3] += a1*bv.w;
        acc[2][0] += a2*bv.x; acc[2][1] += a2*bv.y; acc[2][2] += a2*bv.z; acc[2][3] += a2*bv.w;
        acc[3][0] += a3*bv.x; acc[3][1] += a3*bv.y; acc[3][2] += a3*bv.z; acc[3][3] += a3*bv.w;
    }
    #pragma unroll
    for (int rr = 0; rr < 4; ++rr){
        int m = m0 + ty*4 + rr;
        if (m >= M) continue;
        if (cb0 < 384){
            *(float4*)&KVP[(size_t)m*384 + cb0 + tx*4] =
                make_float4(acc[rr][0], acc[rr][1], acc[rr][2], acc[rr][3]);
        } else {
            int bb = m / NT;
            int c = cb0 - 384 + tx*4;
            float4 pv = *(const float4*)(pq + (size_t)bb*D128 + c);
            *(float4*)&QA[(size_t)m*D128 + c] =
                make_float4(acc[rr][0]+pv.x, acc[rr][1]+pv.y, acc[rr][2]+pv.z, acc[rr][3]+pv.w);
        }
    }
}

// ---------------- sequential decode: 8 waves per batch elem, ONE barrier/step ----------------
// q broadcast via per-wave global load + readlane (no QV LDS, no second barrier);
// O via butterfly+readlane (no O LDS); LGH double-buffered (WAR barrier removed).
// Uniform code path; DPP reductions (R10-verified); VGPR target <= 64.
__global__ __attribute__((amdgpu_flat_work_group_size(TDEC, TDEC)))
void decode(
    const float* __restrict__ QA, const float* __restrict__ KVP,
    const float* __restrict__ wlast, const float* __restrict__ demand,
    const float* __restrict__ capv, const void* p_nd, const void* p_temp,
    int n_steps, float* __restrict__ out)
{
    __shared__ float sm[LDS_FLOATS];
    const int b = blockIdx.x, t = threadIdx.x;
    const int l = t & 63, g = t >> 6;          // lane, wave (= head = dim-block)
    const int qq = l >> 4, d16 = l & 15;       // PV mapping
    const int nd = read_scalar_int(p_nd);
    const float temp = read_scalar_float(p_temp);
    const float capfull = capv[0];
    float dyn = capv[b];
    const long mb = (long)b * NT;
    const bool hasB = (l < NT - 64);           // second-row validity (l < 37)

    // ---- K rows (head g) for n = l, l+64 ----
    float k0[16], k1[16];
    {
        const float* kr = KVP + (mb + l)*384 + g*16;
        #pragma unroll
        for (int j4 = 0; j4 < 4; ++j4){
            float4 a = *(const float4*)(kr + j4*4);
            k0[j4*4+0]=a.x; k0[j4*4+1]=a.y; k0[j4*4+2]=a.z; k0[j4*4+3]=a.w;
        }
    }
    if (hasB){
        const float* kr = KVP + (mb + l + 64)*384 + g*16;
        #pragma unroll
        for (int j4 = 0; j4 < 4; ++j4){
            float4 a = *(const float4*)(kr + j4*4);
            k1[j4*4+0]=a.x; k1[j4*4+1]=a.y; k1[j4*4+2]=a.z; k1[j4*4+3]=a.w;
        }
    } else {
        #pragma unroll
        for (int j = 0; j < 16; ++j) k1[j] = 0.f;
    }
    float kwl1 = 0.f, kwl2 = 0.f;
    #pragma unroll
    for (int j = 0; j < 16; ++j){
        float w = wlast[g*16 + j];
        kwl1 += w*k0[j]; kwl2 += w*k1[j];
    }
    // ---- kp2 rows (dims 16g..16g+16) for n = l, l+64 ----
    float p2a[16], p2b[16];
    {
        const float* kr = KVP + (mb + l)*384 + 256 + g*16;
        #pragma unroll
        for (int j4 = 0; j4 < 4; ++j4){
            float4 a = *(const float4*)(kr + j4*4);
            p2a[j4*4+0]=a.x; p2a[j4*4+1]=a.y; p2a[j4*4+2]=a.z; p2a[j4*4+3]=a.w;
        }
    }
    if (hasB){
        const float* kr = KVP + (mb + l + 64)*384 + 256 + g*16;
        #pragma unroll
        for (int j4 = 0; j4 < 4; ++j4){
            float4 a = *(const float4*)(kr + j4*4);
            p2b[j4*4+0]=a.x; p2b[j4*4+1]=a.y; p2b[j4*4+2]=a.z; p2b[j4*4+3]=a.w;
        }
    } else {
        #pragma unroll
        for (int j = 0; j < 16; ++j) p2b[j] = 0.f;
    }
    // ---- demand + mask registers (redundant across waves) ----
    float dem1 = demand[mb + l];
    float dem2 = hasB ? demand[mb + l + 64] : 0.f;
    float mk1a = 0.f, mk1b = 0.f;
    float m1 = (l < nd) ? 1.f : ((dem1 > dyn) ? 1.f : 0.f);
    float m2 = ((l + 64) < nd) ? 1.f : ((dem2 > dyn) ? 1.f : 0.f);
    int served = 0; float logps = 0.f;

    // ---- stage VH[g][d][n] transposed (n zero-padded to PVP), P pads ----
    for (int i = t; i < 8*112*16; i += TDEC){
        int gg = i / 1792, r = i - gg*1792;
        int n = r >> 4, d = r & 15;            // d inner: coalesced global read
        sm[VH_OFF + gg*VGPP + d*PVP + n] =
            (n < NT) ? KVP[(mb + n)*384 + 128 + gg*16 + d] : 0.f;
    }
    for (int i = t; i < 8*PSTR; i += TDEC) sm[P_OFF + i] = 0.f;
    // initial q slice (index0 = 0): lanes 0-15 of each wave hold q[g*16 + l]
    float qreg = 0.f;
    if (l < 16) qreg = QA[mb*D128 + g*16 + l];
    __syncthreads();

    for (int s = 0; s < n_steps; ++s){
        // ==== P1: q via readlane, compat -> softmax -> PV (wave-internal) ====
        float qk1 = 0.f, qk2 = 0.f;
        #pragma unroll
        for (int j = 0; j < 16; ++j){
            float qj = rdlf(qreg, j);
            qk1 += qj*k0[j]; qk2 += qj*k1[j];
        }
        float c1 = 0.25f*(qk1 + dyn*kwl1);
        if (m1 > 0.f) c1 = -1000000000.0f;
        float c2 = -1000000000.0f;
        if (hasB){
            float a = 0.25f*(qk2 + dyn*kwl2);
            c2 = (m2 > 0.f) ? -1000000000.0f : a;
        }
        float mx = wave_max64(fmaxf(c1, c2));
        float p1 = expf(c1 - mx);
        float p2v = hasB ? expf(c2 - mx) : 0.f;
        float ls = wave_sum64(p1 + p2v);
        sm[P_OFF + g*PSTR + l] = p1;
        if (hasB) sm[P_OFF + g*PSTR + 64 + l] = p2v;
        // same-wave DS ordering: write->read needs no __syncthreads
        float acc = 0.f;
        {
            const float4* pp = (const float4*)&sm[P_OFF + g*PSTR + qq*28];
            const float4* vp = (const float4*)&sm[VH_OFF + g*VGPP + d16*PVP + qq*28];
            #pragma unroll
            for (int i4 = 0; i4 < 7; ++i4){
                float4 pv = pp[i4];
                float4 vv = vp[i4];
                acc += pv.x*vv.x + pv.y*vv.y + pv.z*vv.z + pv.w*vv.w;
            }
        }
        // butterfly: every lane ends with the full sum for its d16 column
        acc += __shfl_xor(acc, 16, 64);
        acc += __shfl_xor(acc, 32, 64);
        float o_own = acc / ls;                // lane j (j<16) holds o[16g + j]

        // ==== P2: logit partials via readlane(o_own) — no O LDS round-trip ====
        float lg1 = 0.f, lg2 = 0.f;
        #pragma unroll
        for (int j = 0; j < 16; ++j){
            float oj = rdlf(o_own, j);
            lg1 += oj*p2a[j]; lg2 += oj*p2b[j];
        }
        {
            float* lgp = &sm[LGH_OFF + (s & 1)*LGB + g*104];
            lgp[l] = lg1;
            if (hasB) lgp[64 + l] = lg2;
        }
        __syncthreads();                       // the ONE barrier per step

        // ==== F: redundant in every wave (each needs bix for its own q fetch) ====
        const float* lgb = &sm[LGH_OFF + (s & 1)*LGB];
        float s1v = 0.f;
        #pragma unroll
        for (int w = 0; w < 8; ++w) s1v += lgb[w*104 + l];
        float s2v = 0.f;
        if (hasB){
            #pragma unroll
            for (int w = 0; w < 8; ++w) s2v += lgb[w*104 + 64 + l];
        }
        float r1 = (m1 > 0.f) ? -3.0e38f : s1v;
        float r2 = hasB ? ((m2 > 0.f) ? -3.0e38f : s2v) : -3.3e38f;
        float bv = r1; int bix = l;
        if (r2 > bv){ bv = r2; bix = l + 64; }
        wave_argmax64(bv, bix);
        // issue next q slice load ASAP (latency hides under bookkeeping + skew)
        if (l < 16) qreg = QA[(mb + bix)*D128 + g*16 + l];
        // save pre-update state for wave0's shadow lse
        float m1o = m1, m2o = m2;
        bool keep_lp = (served < NT - 1);
        // bookkeeping (wave-uniform; readlane, no DS)
        float selv = (bix < 64) ? rdlf(dem1, bix) : rdlf(dem2, bix - 64);
        float vis  = (bix < 64) ? rdlf(mk1a, bix) : rdlf(mk1b, bix - 64);
        bool go = bix < nd;
        float dynN = go ? capfull : (dyn - selv);
        if (!go && vis == 0.f) served++;
        if (bix == l && l >= nd) mk1a = 1.f;
        if (hasB && bix == (l + 64)) mk1b = 1.f;
        bool done = served >= NT - nd;
        float depotf = (go && !done) ? 1.f : 0.f;
        dyn = dynN;
        m1 = fmaxf(mk1a, (dem1 > dyn) ? 1.f : 0.f);
        if (l < nd) m1 = depotf;
        m2 = fmaxf(mk1b, (dem2 > dyn) ? 1.f : 0.f);
        if ((l + 64) < nd) m2 = depotf;
        if (g == 0){
            if (l == 0) out[(size_t)b*n_steps + s] = (float)bix;
            // shadow lse: other waves skew ahead into next P1 (no barrier here)
            float Lm = tanhf(bv * INV_D_CONST) * 10.0f / temp;
            float L1 = (m1o > 0.f) ? (-1000000000.0f / temp)
                                   : (tanhf(s1v * INV_D_CONST) * 10.0f / temp);
            float e1 = expf(L1 - Lm);
            float e2 = 0.f;
            if (hasB){
                float L2 = (m2o > 0.f) ? (-1000000000.0f / temp)
                                       : (tanhf(s2v * INV_D_CONST) * 10.0f / temp);
                e2 = expf(L2 - Lm);
            }
            float ss = wave_sum64(e1 + e2);
            if (keep_lp) logps += -logf(ss);
        }
    }
    if (t == 0) out[(size_t)gridDim.x*n_steps + b] = logps;
}

extern "C" void kernel_launch(void* const* d_in, const int* in_sizes, int n_in,
                              void* d_out, int out_size, void* d_ws, size_t ws_size,
                              hipStream_t stream) {
    const float* enc     = (const float*)d_in[0];
    const float* pool    = (const float*)d_in[1];
    const float* capv    = (const float*)d_in[2];
    const float* demand  = (const float*)d_in[3];
    const float* fc_w    = (const float*)d_in[4];
    const float* fc1_w   = (const float*)d_in[5];
    const float* attn_w  = (const float*)d_in[6];
    const float* attn_k  = (const float*)d_in[7];
    const float* attn_v  = (const float*)d_in[8];
    const float* attn_fc = (const float*)d_in[9];
    const float* prob_k  = (const float*)d_in[10];
    const void*  p_nd    = d_in[12];
    const void*  p_temp  = d_in[13];

    int B = in_sizes[1] / D128;          // pool is (B, D)
    int n_steps = out_size / B - 1;      // out = B*n_steps actions + B logps
    int M = B * NT;

    float* ws    = (float*)d_ws;
    float* Wcat  = ws;                               // 128*512
    float* wlast = Wcat + 128*512;                   // 128
    float* pq    = wlast + 128;                      // B*128
    float* KVP   = pq + (size_t)B*D128;              // M*384
    float* QA    = KVP + (size_t)M*384;              // M*128

    prep_w2<<<129, 512, 0, stream>>>(fc_w, attn_w, prob_k, attn_fc, attn_k, attn_v, Wcat, wlast);
    prep_pq<<<B, 128, 0, stream>>>(pool, fc1_w, attn_w, pq);
    dim3 ggrid((M + 63)/64, 8);
    gemm_prep<<<ggrid, 256, 0, stream>>>(enc, Wcat, pq, M, KVP, QA);

    decode<<<B, TDEC, 0, stream>>>(QA, KVP, wlast, demand, capv, p_nd, p_temp,
                                   n_steps, (float*)d_out);
}

// Round 12
// 984.025 us; speedup vs baseline: 1.8775x; 1.0943x over previous
//
#include <hip/hip_runtime.h>

#define D128 128
#define NT 101
#define TDEC 512
#define PSTR 112            // padded p row: 4 quarters of 28 floats (16B aligned)
#define PVP 116             // VH inner (n) pitch, mult of 4 -> aligned b128
#define VGPP (16*PVP)       // per-head VH pitch = 1856 floats
#define LGP12 12            // packed LGH pitch: [node][wave], 12 -> b128-aligned, bank-clean
#define LGB12 (104*LGP12)   // one LGH buffer

// ---- decode LDS layout (floats) ----
#define VH_OFF   0                       // [8][16 d][PVP n] V slices (n zero-padded)
#define P_OFF    (VH_OFF + 8*VGPP)       // 8 x PSTR
#define LGH_OFF  (P_OFF + 8*PSTR)        // 2 x 104 x 12 double-buffered logit partials
#define LDS_FLOATS (LGH_OFF + 2*LGB12)   // 18240 floats = 72,960 B -> 2 WG/CU

#define INV_D_CONST 0.08838834764831845f
#define NEG_INF __int_as_float(0xff800000)

__device__ __forceinline__ int read_scalar_int(const void* p){
    unsigned u = *(const unsigned*)p;
    if (u < 1000000u) return (int)u;
    return (int)__uint_as_float(u);
}
__device__ __forceinline__ float read_scalar_float(const void* p){
    unsigned u = *(const unsigned*)p;
    if (u < 1000000u) return (float)(int)u;
    return __uint_as_float(u);
}

// ---- DPP cross-lane helpers (VALU pipe, no DS) — verified correct in R10/R11 ----
template<int C> __device__ __forceinline__ float dppf(float x){
    return __int_as_float(__builtin_amdgcn_update_dpp(
        __float_as_int(x), __float_as_int(x), C, 0xF, 0xF, false));
}
template<int C> __device__ __forceinline__ int dppi(int x){
    return __builtin_amdgcn_update_dpp(x, x, C, 0xF, 0xF, false);
}
template<int C, int RM> __device__ __forceinline__ float dppmf(float idv, float x){
    return __int_as_float(__builtin_amdgcn_update_dpp(
        __float_as_int(idv), __float_as_int(x), C, RM, 0xF, false));
}
template<int C, int RM> __device__ __forceinline__ int dppmi(int idv, int x){
    return __builtin_amdgcn_update_dpp(idv, x, C, RM, 0xF, false);
}
__device__ __forceinline__ float rdlf(float v, int lane){
    return __int_as_float(__builtin_amdgcn_readlane(__float_as_int(v), lane));
}
// Canonical wave64 reductions: 4 mirror stages (rows uniform), bcast15/31 merge.
__device__ __forceinline__ float wave_sum64(float v){
    v += dppf<0xB1>(v); v += dppf<0x4E>(v); v += dppf<0x141>(v); v += dppf<0x140>(v);
    v += dppmf<0x142,0xa>(0.f, v);
    v += dppmf<0x143,0x8>(0.f, v);
    return rdlf(v, 63);
}
__device__ __forceinline__ float wave_max64(float v){
    v = fmaxf(v, dppf<0xB1>(v)); v = fmaxf(v, dppf<0x4E>(v));
    v = fmaxf(v, dppf<0x141>(v)); v = fmaxf(v, dppf<0x140>(v));
    v = fmaxf(v, dppmf<0x142,0xa>(NEG_INF, v));
    v = fmaxf(v, dppmf<0x143,0x8>(NEG_INF, v));
    return rdlf(v, 63);
}
__device__ __forceinline__ void wave_argmax64(float& v, int& i){
    { float ov = dppf<0xB1>(v);  int oi = dppi<0xB1>(i);  if (ov>v || (ov==v && oi<i)){v=ov;i=oi;} }
    { float ov = dppf<0x4E>(v);  int oi = dppi<0x4E>(i);  if (ov>v || (ov==v && oi<i)){v=ov;i=oi;} }
    { float ov = dppf<0x141>(v); int oi = dppi<0x141>(i); if (ov>v || (ov==v && oi<i)){v=ov;i=oi;} }
    { float ov = dppf<0x140>(v); int oi = dppi<0x140>(i); if (ov>v || (ov==v && oi<i)){v=ov;i=oi;} }
    { float ov = dppmf<0x142,0xa>(NEG_INF, v); int oi = dppmi<0x142,0xa>(0, i);
      if (ov>v || (ov==v && oi<i)){v=ov;i=oi;} }
    { float ov = dppmf<0x143,0x8>(NEG_INF, v); int oi = dppmi<0x143,0x8>(0, i);
      if (ov>v || (ov==v && oi<i)){v=ov;i=oi;} }
    v = rdlf(v, 63);
    i = __builtin_amdgcn_readlane(i, 63);
}

// ---------------- weight folding (unchanged) ----------------
__global__ __launch_bounds__(512) void prep_w2(
        const float* __restrict__ fc_w, const float* __restrict__ attn_w,
        const float* __restrict__ prob_k, const float* __restrict__ attn_fc,
        const float* __restrict__ attn_k, const float* __restrict__ attn_v,
        float* __restrict__ Wcat, float* __restrict__ wlast){
    int i = blockIdx.x, t = threadIdx.x;
    if (i < 128){
        if (t < 128){
            Wcat[i*512 + t] = attn_k[i*D128 + t];
        } else if (t < 256){
            int j = t - 128;
            Wcat[i*512 + 128 + j] = attn_v[i*D128 + j];
        } else if (t < 384){
            int j = t - 256; float acc = 0.f;
            for (int e = 0; e < D128; ++e) acc += prob_k[i*D128+e]*attn_fc[j*D128+e];
            Wcat[i*512 + 256 + j] = acc;
        } else {
            int j = t - 384; float acc = 0.f;
            for (int e = 0; e < D128; ++e) acc += fc_w[i*D128+e]*attn_w[e*D128+j];
            Wcat[i*512 + 384 + j] = acc;
        }
    } else if (t < 128){
        float acc = 0.f;
        for (int e = 0; e < D128; ++e) acc += fc_w[128*D128+e]*attn_w[e*D128+t];
        wlast[t] = acc;
    }
}

__global__ __launch_bounds__(128) void prep_pq(
        const float* __restrict__ pool, const float* __restrict__ fc1_w,
        const float* __restrict__ attn_w, float* __restrict__ pq){
    __shared__ float s1[128], s2[128];
    int b = blockIdx.x, t = threadIdx.x;
    s1[t] = pool[(size_t)b*D128 + t];
    __syncthreads();
    float a = 0.f;
    for (int i = 0; i < D128; ++i) a += s1[i]*fc1_w[i*D128 + t];
    s2[t] = a;
    __syncthreads();
    float a2 = 0.f;
    for (int i = 0; i < D128; ++i) a2 += s2[i]*attn_w[i*D128 + t];
    pq[(size_t)b*D128 + t] = a2;
}

__global__ __launch_bounds__(256) void gemm_prep(
        const float* __restrict__ enc, const float* __restrict__ Wcat,
        const float* __restrict__ pq, int M,
        float* __restrict__ KVP, float* __restrict__ QA){
    __shared__ float As[64*132];
    const int t = threadIdx.x;
    const int m0 = blockIdx.x * 64;
    const int cb0 = blockIdx.y * 64;
    for (int i = t; i < 64*32; i += 256){
        int row = i >> 5, c4 = (i & 31) << 2;
        float4 val = make_float4(0.f,0.f,0.f,0.f);
        if (m0 + row < M) val = *(const float4*)(enc + (size_t)(m0+row)*D128 + c4);
        *(float4*)&As[row*132 + c4] = val;
    }
    __syncthreads();
    const int tx = t & 15, ty = t >> 4;
    float acc[4][4];
    #pragma unroll
    for (int i = 0; i < 4; ++i)
        #pragma unroll
        for (int j = 0; j < 4; ++j) acc[i][j] = 0.f;
    const float* wp = Wcat + cb0 + tx*4;
    #pragma unroll 4
    for (int k = 0; k < 128; ++k){
        float4 bv = *(const float4*)(wp + (size_t)k*512);
        float a0 = As[(ty*4+0)*132 + k];
        float a1 = As[(ty*4+1)*132 + k];
        float a2 = As[(ty*4+2)*132 + k];
        float a3 = As[(ty*4+3)*132 + k];
        acc[0][0] += a0*bv.x; acc[0][1] += a0*bv.y; acc[0][2] += a0*bv.z; acc[0][3] += a0*bv.w;
        acc[1][0] += a1*bv.x; acc[1][1] += a1*bv.y; acc[1][2] += a1*bv.z; acc[1][3] += a1*bv.w;
        acc[2][0] += a2*bv.x; acc[2][1] += a2*bv.y; acc[2][2] += a2*bv.z; acc[2][3] += a2*bv.w;
        acc[3][0] += a3*bv.x; acc[3][1] += a3*bv.y; acc[3][2] += a3*bv.z; acc[3][3] += a3*bv.w;
    }
    #pragma unroll
    for (int rr = 0; rr < 4; ++rr){
        int m = m0 + ty*4 + rr;
        if (m >= M) continue;
        if (cb0 < 384){
            *(float4*)&KVP[(size_t)m*384 + cb0 + tx*4] =
                make_float4(acc[rr][0], acc[rr][1], acc[rr][2], acc[rr][3]);
        } else {
            int bb = m / NT;
            int c = cb0 - 384 + tx*4;
            float4 pv = *(const float4*)(pq + (size_t)bb*D128 + c);
            *(float4*)&QA[(size_t)m*D128 + c] =
                make_float4(acc[rr][0]+pv.x, acc[rr][1]+pv.y, acc[rr][2]+pv.z, acc[rr][3]+pv.w);
        }
    }
}

// ---------------- sequential decode: 8 waves per batch elem, ONE barrier/step ----------------
// R11 structure (VGPR=64, 2 WG/CU, VALU-bound) + instruction diet:
// LGH packed [node][wave] pitch-12 (F: 4 b128 reads), __expf softmax, Newton-rcp
// normalize, fast-math logp tail (output-only path).
__global__ __attribute__((amdgpu_flat_work_group_size(TDEC, TDEC)))
void decode(
    const float* __restrict__ QA, const float* __restrict__ KVP,
    const float* __restrict__ wlast, const float* __restrict__ demand,
    const float* __restrict__ capv, const void* p_nd, const void* p_temp,
    int n_steps, float* __restrict__ out)
{
    __shared__ float sm[LDS_FLOATS];
    const int b = blockIdx.x, t = threadIdx.x;
    const int l = t & 63, g = t >> 6;          // lane, wave (= head = dim-block)
    const int qq = l >> 4, d16 = l & 15;       // PV mapping
    const int nd = read_scalar_int(p_nd);
    const float temp = read_scalar_float(p_temp);
    const float invtemp = 1.0f / temp;         // host-scalar; logp path only
    const float capfull = capv[0];
    float dyn = capv[b];
    const long mb = (long)b * NT;
    const bool hasB = (l < NT - 64);           // second-row validity (l < 37)

    // ---- K rows (head g) for n = l, l+64 ----
    float k0[16], k1[16];
    {
        const float* kr = KVP + (mb + l)*384 + g*16;
        #pragma unroll
        for (int j4 = 0; j4 < 4; ++j4){
            float4 a = *(const float4*)(kr + j4*4);
            k0[j4*4+0]=a.x; k0[j4*4+1]=a.y; k0[j4*4+2]=a.z; k0[j4*4+3]=a.w;
        }
    }
    if (hasB){
        const float* kr = KVP + (mb + l + 64)*384 + g*16;
        #pragma unroll
        for (int j4 = 0; j4 < 4; ++j4){
            float4 a = *(const float4*)(kr + j4*4);
            k1[j4*4+0]=a.x; k1[j4*4+1]=a.y; k1[j4*4+2]=a.z; k1[j4*4+3]=a.w;
        }
    } else {
        #pragma unroll
        for (int j = 0; j < 16; ++j) k1[j] = 0.f;
    }
    float kwl1 = 0.f, kwl2 = 0.f;
    #pragma unroll
    for (int j = 0; j < 16; ++j){
        float w = wlast[g*16 + j];
        kwl1 += w*k0[j]; kwl2 += w*k1[j];
    }
    // ---- kp2 rows (dims 16g..16g+16) for n = l, l+64 ----
    float p2a[16], p2b[16];
    {
        const float* kr = KVP + (mb + l)*384 + 256 + g*16;
        #pragma unroll
        for (int j4 = 0; j4 < 4; ++j4){
            float4 a = *(const float4*)(kr + j4*4);
            p2a[j4*4+0]=a.x; p2a[j4*4+1]=a.y; p2a[j4*4+2]=a.z; p2a[j4*4+3]=a.w;
        }
    }
    if (hasB){
        const float* kr = KVP + (mb + l + 64)*384 + 256 + g*16;
        #pragma unroll
        for (int j4 = 0; j4 < 4; ++j4){
            float4 a = *(const float4*)(kr + j4*4);
            p2b[j4*4+0]=a.x; p2b[j4*4+1]=a.y; p2b[j4*4+2]=a.z; p2b[j4*4+3]=a.w;
        }
    } else {
        #pragma unroll
        for (int j = 0; j < 16; ++j) p2b[j] = 0.f;
    }
    // ---- demand + mask registers (redundant across waves) ----
    float dem1 = demand[mb + l];
    float dem2 = hasB ? demand[mb + l + 64] : 0.f;
    float mk1a = 0.f, mk1b = 0.f;
    float m1 = (l < nd) ? 1.f : ((dem1 > dyn) ? 1.f : 0.f);
    float m2 = ((l + 64) < nd) ? 1.f : ((dem2 > dyn) ? 1.f : 0.f);
    int served = 0; float logps = 0.f;

    // ---- stage VH[g][d][n] transposed (n zero-padded to PVP), P pads ----
    for (int i = t; i < 8*112*16; i += TDEC){
        int gg = i / 1792, r = i - gg*1792;
        int n = r >> 4, d = r & 15;            // d inner: coalesced global read
        sm[VH_OFF + gg*VGPP + d*PVP + n] =
            (n < NT) ? KVP[(mb + n)*384 + 128 + gg*16 + d] : 0.f;
    }
    for (int i = t; i < 8*PSTR; i += TDEC) sm[P_OFF + i] = 0.f;
    // initial q slice (index0 = 0): lanes 0-15 of each wave hold q[g*16 + l]
    float qreg = 0.f;
    if (l < 16) qreg = QA[mb*D128 + g*16 + l];
    __syncthreads();

    for (int s = 0; s < n_steps; ++s){
        // ==== P1: q via readlane, compat -> softmax -> PV (wave-internal) ====
        float qk1 = 0.f, qk2 = 0.f;
        #pragma unroll
        for (int j = 0; j < 16; ++j){
            float qj = rdlf(qreg, j);
            qk1 += qj*k0[j]; qk2 += qj*k1[j];
        }
        float c1 = 0.25f*(qk1 + dyn*kwl1);
        if (m1 > 0.f) c1 = -1000000000.0f;
        float c2 = -1000000000.0f;
        if (hasB){
            float a = 0.25f*(qk2 + dyn*kwl2);
            c2 = (m2 > 0.f) ? -1000000000.0f : a;
        }
        float mx = wave_max64(fmaxf(c1, c2));
        float p1 = __expf(c1 - mx);
        float p2v = hasB ? __expf(c2 - mx) : 0.f;
        float ls = wave_sum64(p1 + p2v);
        sm[P_OFF + g*PSTR + l] = p1;
        if (hasB) sm[P_OFF + g*PSTR + 64 + l] = p2v;
        // same-wave DS ordering: write->read needs no __syncthreads
        float acc = 0.f;
        {
            const float4* pp = (const float4*)&sm[P_OFF + g*PSTR + qq*28];
            const float4* vp = (const float4*)&sm[VH_OFF + g*VGPP + d16*PVP + qq*28];
            #pragma unroll
            for (int i4 = 0; i4 < 7; ++i4){
                float4 pv = pp[i4];
                float4 vv = vp[i4];
                acc += pv.x*vv.x + pv.y*vv.y + pv.z*vv.z + pv.w*vv.w;
            }
        }
        // butterfly: every lane ends with the full sum for its d16 column
        acc += __shfl_xor(acc, 16, 64);
        acc += __shfl_xor(acc, 32, 64);
        // ls is wave-uniform: Newton-refined reciprocal, 1 mul per lane
        float lr = __builtin_amdgcn_rcpf(ls);
        lr = lr * (2.0f - ls*lr);
        float o_own = acc * lr;                // lane j (j<16) holds o[16g + j]

        // ==== P2: logit partials via readlane(o_own) — no O LDS round-trip ====
        float lg1 = 0.f, lg2 = 0.f;
        #pragma unroll
        for (int j = 0; j < 16; ++j){
            float oj = rdlf(o_own, j);
            lg1 += oj*p2a[j]; lg2 += oj*p2b[j];
        }
        {
            float* lgp = &sm[LGH_OFF + (s & 1)*LGB12];
            lgp[l*LGP12 + g] = lg1;
            if (hasB) lgp[(64 + l)*LGP12 + g] = lg2;
        }
        __syncthreads();                       // the ONE barrier per step

        // ==== F: redundant in every wave (each needs bix for its own q fetch) ====
        const float* lgb = &sm[LGH_OFF + (s & 1)*LGB12];
        float s1v, s2v = 0.f;
        {   // packed reads; sums stay strictly left-to-right (w=0..7) = bitwise same
            float4 A = *(const float4*)&lgb[l*LGP12];
            s1v = A.x; s1v += A.y; s1v += A.z; s1v += A.w;
            float4 Bq = *(const float4*)&lgb[l*LGP12 + 4];
            s1v += Bq.x; s1v += Bq.y; s1v += Bq.z; s1v += Bq.w;
        }
        if (hasB){
            float4 A = *(const float4*)&lgb[(64 + l)*LGP12];
            s2v = A.x; s2v += A.y; s2v += A.z; s2v += A.w;
            float4 Bq = *(const float4*)&lgb[(64 + l)*LGP12 + 4];
            s2v += Bq.x; s2v += Bq.y; s2v += Bq.z; s2v += Bq.w;
        }
        float r1 = (m1 > 0.f) ? -3.0e38f : s1v;
        float r2 = hasB ? ((m2 > 0.f) ? -3.0e38f : s2v) : -3.3e38f;
        float bv = r1; int bix = l;
        if (r2 > bv){ bv = r2; bix = l + 64; }
        wave_argmax64(bv, bix);
        // issue next q slice load ASAP (latency hides under bookkeeping + skew)
        if (l < 16) qreg = QA[(mb + bix)*D128 + g*16 + l];
        // save pre-update state for wave0's shadow lse
        float m1o = m1, m2o = m2;
        bool keep_lp = (served < NT - 1);
        // bookkeeping (wave-uniform; readlane, no DS)
        float selv = (bix < 64) ? rdlf(dem1, bix) : rdlf(dem2, bix - 64);
        float vis  = (bix < 64) ? rdlf(mk1a, bix) : rdlf(mk1b, bix - 64);
        bool go = bix < nd;
        float dynN = go ? capfull : (dyn - selv);
        if (!go && vis == 0.f) served++;
        if (bix == l && l >= nd) mk1a = 1.f;
        if (hasB && bix == (l + 64)) mk1b = 1.f;
        bool done = served >= NT - nd;
        float depotf = (go && !done) ? 1.f : 0.f;
        dyn = dynN;
        m1 = fmaxf(mk1a, (dem1 > dyn) ? 1.f : 0.f);
        if (l < nd) m1 = depotf;
        m2 = fmaxf(mk1b, (dem2 > dyn) ? 1.f : 0.f);
        if ((l + 64) < nd) m2 = depotf;
        if (g == 0){
            if (l == 0) out[(size_t)b*n_steps + s] = (float)bix;
            // shadow lse (logp OUTPUT only — fast-math safe, no feedback to actions)
            // tanh(x) = 1 - 2/(e^2x + 1)
            float tm = 1.0f - 2.0f*__builtin_amdgcn_rcpf(__expf(2.0f*bv*INV_D_CONST) + 1.0f);
            float Lm = tm * 10.0f * invtemp;
            float L1;
            if (m1o > 0.f) L1 = -1000000000.0f * invtemp;
            else {
                float t1 = 1.0f - 2.0f*__builtin_amdgcn_rcpf(__expf(2.0f*s1v*INV_D_CONST) + 1.0f);
                L1 = t1 * 10.0f * invtemp;
            }
            float e1 = __expf(L1 - Lm);
            float e2 = 0.f;
            if (hasB){
                float L2;
                if (m2o > 0.f) L2 = -1000000000.0f * invtemp;
                else {
                    float t2 = 1.0f - 2.0f*__builtin_amdgcn_rcpf(__expf(2.0f*s2v*INV_D_CONST) + 1.0f);
                    L2 = t2 * 10.0f * invtemp;
                }
                e2 = __expf(L2 - Lm);
            }
            float ss = wave_sum64(e1 + e2);
            if (keep_lp) logps += -__logf(ss);
        }
    }
    if (t == 0) out[(size_t)gridDim.x*n_steps + b] = logps;
}

extern "C" void kernel_launch(void* const* d_in, const int* in_sizes, int n_in,
                              void* d_out, int out_size, void* d_ws, size_t ws_size,
                              hipStream_t stream) {
    const float* enc     = (const float*)d_in[0];
    const float* pool    = (const float*)d_in[1];
    const float* capv    = (const float*)d_in[2];
    const float* demand  = (const float*)d_in[3];
    const float* fc_w    = (const float*)d_in[4];
    const float* fc1_w   = (const float*)d_in[5];
    const float* attn_w  = (const float*)d_in[6];
    const float* attn_k  = (const float*)d_in[7];
    const float* attn_v  = (const float*)d_in[8];
    const float* attn_fc = (const float*)d_in[9];
    const float* prob_k  = (const float*)d_in[10];
    const void*  p_nd    = d_in[12];
    const void*  p_temp  = d_in[13];

    int B = in_sizes[1] / D128;          // pool is (B, D)
    int n_steps = out_size / B - 1;      // out = B*n_steps actions + B logps
    int M = B * NT;

    float* ws    = (float*)d_ws;
    float* Wcat  = ws;                               // 128*512
    float* wlast = Wcat + 128*512;                   // 128
    float* pq    = wlast + 128;                      // B*128
    float* KVP   = pq + (size_t)B*D128;              // M*384
    float* QA    = KVP + (size_t)M*384;              // M*128

    prep_w2<<<129, 512, 0, stream>>>(fc_w, attn_w, prob_k, attn_fc, attn_k, attn_v, Wcat, wlast);
    prep_pq<<<B, 128, 0, stream>>>(pool, fc1_w, attn_w, pq);
    dim3 ggrid((M + 63)/64, 8);
    gemm_prep<<<ggrid, 256, 0, stream>>>(enc, Wcat, pq, M, KVP, QA);

    decode<<<B, TDEC, 0, stream>>>(QA, KVP, wlast, demand, capv, p_nd, p_temp,
                                   n_steps, (float*)d_out);
}